// Round 5
// baseline (334.877 us; speedup 1.0000x reference)
//
#include <hip/hip_runtime.h>
#include <hip/hip_bf16.h>
#include <stdint.h>

// OFPenalty fused: per-batch Gram (49x49 from 2048x49) + two 9-step power
// iterations + penalty in ONE kernel.
//
// R5 = R4 gram (validated, verbatim) + R3 fusion mechanism (validated:
// counter + threadfence, 4th arriver per batch runs eigen) + eigen with
// float4 xv broadcasts. Controlled experiment: if dur drops ~30-45 us, the
// missing time was eigen+dispatch gaps; if neutral and the fused kernel
// shows in top-5 at >60 us, gram's DMA pipeline is the hog.

#define BATCH 256
#define CDIM  2048
#define NDIM  49
#define QK    512                    // C rows per block (2048/4)
#define CHUNK 64                     // k rows per LDS stage
#define NCHUNK (QK / CHUNK)          // 8
#define CH_FLOATS (CHUNK * NDIM)     // 3136
#define CH_SLOTS  (CH_FLOATS / 4)    // 784 16B DMA slots
#define TN    56                     // tile n capacity (>=49; rows clamp)
#define NSLICE (8 * TN)              // 448 (g,n) cells per chunk
#define TILE_BYTES (8 * TN * 8 * 2)  // 7168 per hi/lo tile
#define RAW_BYTES (2 * CH_FLOATS * 4)// 25088 (dbuf)
#define PSIZE (NDIM * NDIM)          // 2401
#define ESTR  65                     // Ebuf row stride (f32)
#define ASTR  53                     // eigen A row stride (f32; odd -> <=2-way)
#define CNT_OFF (1024 * PSIZE)       // float offset of counters in ws

typedef __bf16 bf16x8 __attribute__((ext_vector_type(8)));
typedef float  f32x16 __attribute__((ext_vector_type(16)));

__device__ inline void async_load16(const float* g, float* l) {
  __builtin_amdgcn_global_load_lds(
      (const __attribute__((address_space(1))) void*)g,
      (__attribute__((address_space(3))) void*)l,
      16 /*bytes*/, 0 /*offset*/, 0 /*aux*/);
}

__global__ __launch_bounds__(256, 4) void ofpenalty_fused(
    const float* __restrict__ x, const float* __restrict__ x0,
    float* __restrict__ partial, unsigned int* __restrict__ cnt,
    float* __restrict__ acc, unsigned int* __restrict__ done,
    float* __restrict__ out) {
  // 39424 B -> 4 blocks/CU. Gram: raw dbuf | tileH | tileL.
  // Epilogue Ebuf (64x65 f32) and eigen {Aeig, xv} overlay the raw region
  // (dead after the K-loop), separated by barriers.
  __shared__ __align__(16) char smem[RAW_BYTES + 2 * TILE_BYTES];
  __shared__ int flag;
  float*  raw0 = (float*)smem;
  float*  raw1 = (float*)(smem + CH_FLOATS * 4);
  __bf16* tH   = (__bf16*)(smem + RAW_BYTES);
  __bf16* tL   = (__bf16*)(smem + RAW_BYTES + TILE_BYTES);
  float*  Ebuf = (float*)smem;
  float*  Aeig = (float*)smem;
  float*  xv   = (float*)(smem + 10400);   // 16B-aligned, past Aeig (10388 B)

  const int tid   = threadIdx.x;
  const int bidx  = blockIdx.x;       // 0..1023
  const int batch = bidx >> 2;
  const int q     = bidx & 3;
  const int w     = tid >> 6;         // wave 0..3
  const int lane  = tid & 63;
  const int ln    = lane & 31;
  const int hf    = lane >> 5;
  const int qm = w >> 1, qn = w & 1;
  const int rowA = min(qm * 32 + ln, TN - 1);  // clamped rows feed discarded C
  const int rowB = min(qn * 32 + ln, TN - 1);
  const int nOut = qn * 32 + ln;

  const float* gbase = x + ((size_t)batch * CDIM + (size_t)q * QK) * NDIM;

  f32x16 c1, cE;
#pragma unroll
  for (int i = 0; i < 16; ++i) { c1[i] = 0.f; cE[i] = 0.f; }

  // convert-pass slice assignment (fixed per thread)
  const int s1ok = (tid < NSLICE - 256);       // 192 threads take 2nd slice
  const int n0 = tid % TN,         g0 = tid / TN;
  const int n1 = (256 + tid) % TN, g1 = (256 + tid) / TN;

  // prologue DMA: chunk 0 -> raw0
#pragma unroll
  for (int i = 0; i < 4; ++i) {
    int slot = i * 256 + tid;
    if (slot < CH_SLOTS) async_load16(gbase + slot * 4, raw0 + slot * 4);
  }

  for (int ch = 0; ch < NCHUNK; ++ch) {
    float* cur = (ch & 1) ? raw1 : raw0;
    float* nxt = (ch & 1) ? raw0 : raw1;
    __syncthreads();  // barrier A: DMA(ch) drained+visible; tiles consumed

    if (ch + 1 < NCHUNK) {  // DMA chunk ch+1
      const float* gch = gbase + (size_t)(ch + 1) * CH_FLOATS;
#pragma unroll
      for (int i = 0; i < 4; ++i) {
        int slot = i * 256 + tid;
        if (slot < CH_SLOTS) async_load16(gch + slot * 4, nxt + slot * 4);
      }
    }

    // convert-once: raw fp32 -> hi/lo bf16 fragment cells [g][n][8]
    if (n0 < NDIM) {
      const float* rp = cur + g0 * 8 * NDIM + n0;
      bf16x8 h8, l8;
#pragma unroll
      for (int j = 0; j < 8; ++j) {
        float v = rp[j * NDIM];
        __bf16 h = (__bf16)v;
        h8[j] = h;
        l8[j] = (__bf16)(v - (float)h);
      }
      *(bf16x8*)(tH + (g0 * TN + n0) * 8) = h8;
      *(bf16x8*)(tL + (g0 * TN + n0) * 8) = l8;
    }
    if (s1ok && n1 < NDIM) {
      const float* rp = cur + g1 * 8 * NDIM + n1;
      bf16x8 h8, l8;
#pragma unroll
      for (int j = 0; j < 8; ++j) {
        float v = rp[j * NDIM];
        __bf16 h = (__bf16)v;
        h8[j] = h;
        l8[j] = (__bf16)(v - (float)h);
      }
      *(bf16x8*)(tH + (g1 * TN + n1) * 8) = h8;
      *(bf16x8*)(tL + (g1 * TN + n1) * 8) = l8;
    }
    __syncthreads();  // barrier B: tiles ready

#pragma unroll
    for (int g2 = 0; g2 < 4; ++g2) {
      const int g = g2 * 2 + hf;     // k = g2*16 + hf*8 + j
      bf16x8 ah = *(const bf16x8*)(tH + (g * TN + rowA) * 8);
      bf16x8 bh;
      if (qm == qn) bh = ah;         // diagonal quadrant reuse
      else          bh = *(const bf16x8*)(tH + (g * TN + rowB) * 8);
      bf16x8 bl = *(const bf16x8*)(tL + (g * TN + rowB) * 8);
      c1 = __builtin_amdgcn_mfma_f32_32x32x16_bf16(ah, bh, c1, 0, 0, 0);
      cE = __builtin_amdgcn_mfma_f32_32x32x16_bf16(ah, bl, cE, 0, 0, 0);
    }
  }

  // Epilogue: ATA = c1 + E + E^T; E^T via LDS transpose (raw is dead).
  __syncthreads();
#pragma unroll
  for (int r = 0; r < 16; ++r) {
    const int mm = qm * 32 + (r & 3) + 8 * (r >> 2) + 4 * hf;
    Ebuf[mm * ESTR + nOut] = cE[r];
  }
  __syncthreads();
  float* outp = partial + (size_t)bidx * PSIZE;
#pragma unroll
  for (int r = 0; r < 16; ++r) {
    const int mm = qm * 32 + (r & 3) + 8 * (r >> 2) + 4 * hf;
    if (mm < NDIM && nOut < NDIM)
      outp[mm * NDIM + nOut] = c1[r] + cE[r] + Ebuf[nOut * ESTR + mm];
  }

  // publish tile, bump batch counter; 4th arriver runs eigen (R3-validated)
  __threadfence();
  __syncthreads();
  if (tid == 0) {
    unsigned int old = atomicAdd(&cnt[batch], 1u);
    flag = (old == 3u) ? 1 : 0;
  }
  __syncthreads();
  if (!flag) return;
  __threadfence();  // acquire: other blocks' partial tiles visible

  // ---- eigen phase ----
  const float* p0 = partial + (size_t)(batch * 4) * PSIZE;
  for (int idx = tid; idx < PSIZE; idx += 256) {
    int r = idx / NDIM, c = idx - r * NDIM;
    float v = 0.f;
#pragma unroll
    for (int qq = 0; qq < 4; ++qq) v += p0[qq * PSIZE + idx];
    Aeig[r * ASTR + c] = v;
  }
  if (tid < NDIM) xv[tid] = x0[batch * NDIM + tid];
  __syncthreads();

  const int t = tid;
  auto rayleigh_power = [&](float shift) -> float {
    for (int it = 0; it < 9; ++it) {
      float y = 0.f;
      if (t < NDIM) {
        const float* Ar = &Aeig[t * ASTR];
        const float4* xv4 = (const float4*)xv;
#pragma unroll
        for (int j = 0; j < 12; ++j) {       // broadcast float4 reads of xv
          float4 xq = xv4[j];
          y = fmaf(Ar[4 * j + 0], xq.x, y);
          y = fmaf(Ar[4 * j + 1], xq.y, y);
          y = fmaf(Ar[4 * j + 2], xq.z, y);
          y = fmaf(Ar[4 * j + 3], xq.w, y);
        }
        y = fmaf(Ar[48], xv[48], y);
        y -= shift * xv[t];
      }
      float s = y * y;
#pragma unroll
      for (int o = 32; o; o >>= 1) s += __shfl_xor(s, o, 64);
      float nrm = fmaxf(sqrtf(s), 1e-12f);  // F.normalize eps
      __syncthreads();
      if (t < NDIM) xv[t] = y / nrm;
      __syncthreads();
    }
    float yy = 0.f;
    if (t < NDIM) {
      const float* Ar = &Aeig[t * ASTR];
#pragma unroll 7
      for (int k = 0; k < NDIM; ++k) yy = fmaf(Ar[k], xv[k], yy);
      yy -= shift * xv[t];
    }
    float num = (t < NDIM) ? yy * xv[t] : 0.f;
    float den = (t < NDIM) ? xv[t] * xv[t] : 0.f;
#pragma unroll
    for (int o = 32; o; o >>= 1) {
      num += __shfl_xor(num, o, 64);
      den += __shfl_xor(den, o, 64);
    }
    return num / den;
  };

  float largest = rayleigh_power(0.f);
  float tmp = rayleigh_power(largest);  // warm start: xv == x1 already
  float smallest = tmp + largest;

  if (t == 0) {
    float r = largest / smallest - 1.f;
    atomicAdd(acc, r * r * (1.0f / (float)BATCH));  // BETA = 1
    __threadfence();
    unsigned int od = atomicAdd(done, 1u);
    if (od == BATCH - 1) {
      __threadfence();
      out[0] = atomicAdd(acc, 0.0f);  // old value == full sum
    }
  }
}

extern "C" void kernel_launch(void* const* d_in, const int* in_sizes, int n_in,
                              void* d_out, int out_size, void* d_ws,
                              size_t ws_size, hipStream_t stream) {
  const float* x  = (const float*)d_in[0];   // [256,2048,7,7] fp32
  const float* x0 = (const float*)d_in[1];   // [256,49,1] fp32 (pre-normalized)
  float* out = (float*)d_out;                // scalar fp32
  float* partial = (float*)d_ws;             // 1024 * 2401 f32 = 9.83 MB
  unsigned int* cnt  = (unsigned int*)(partial + CNT_OFF);  // 256 u32
  float*        acc  = (float*)(cnt + 256);                 // 1 f32
  unsigned int* done = (unsigned int*)(cnt + 257);          // 1 u32

  hipMemsetAsync((void*)cnt, 0, 258 * sizeof(unsigned int), stream);
  ofpenalty_fused<<<1024, 256, 0, stream>>>(x, x0, partial, cnt, acc, done, out);
}

// Round 6
// 198.126 us; speedup vs baseline: 1.6902x; 1.6902x over previous
//
#include <hip/hip_runtime.h>
#include <hip/hip_bf16.h>
#include <stdint.h>

// OFPenalty: per-batch Gram (49x49 from 2048x49) -> two 9-step power
// iterations -> penalty scalar.
//
// R6 = R4 two-kernel structure VERBATIM (validated best, 179.3 us), with
// gram launched TWICE (idempotent) as a timing probe: delta vs R4 measures
// one gram dispatch + node gap directly, splitting the unexplained ~55 us
// between gram and eigen/gaps. (R5 proved cross-block fusion via device
// fences costs ~180 us in L2 flush storms — two-kernel is the right shape.)

#define BATCH 256
#define CDIM  2048
#define NDIM  49
#define QK    512                    // C rows per block (2048/4)
#define CHUNK 64                     // k rows per LDS stage
#define NCHUNK (QK / CHUNK)          // 8
#define CH_FLOATS (CHUNK * NDIM)     // 3136
#define CH_SLOTS  (CH_FLOATS / 4)    // 784 16B DMA slots
#define TN    56                     // tile n capacity (>=49; rows clamp)
#define NSLICE (8 * TN)              // 448 (g,n) cells per chunk
#define TILE_BYTES (8 * TN * 8 * 2)  // 7168 per hi/lo tile
#define RAW_BYTES (2 * CH_FLOATS * 4)// 25088 (dbuf)
#define PSIZE (NDIM * NDIM)          // 2401
#define ESTR  65                     // Ebuf row stride (f32)
#define ASTR  53                     // eigen A row stride (f32)

typedef __bf16 bf16x8 __attribute__((ext_vector_type(8)));
typedef float  f32x16 __attribute__((ext_vector_type(16)));

__device__ inline void async_load16(const float* g, float* l) {
  __builtin_amdgcn_global_load_lds(
      (const __attribute__((address_space(1))) void*)g,
      (__attribute__((address_space(3))) void*)l,
      16 /*bytes*/, 0 /*offset*/, 0 /*aux*/);
}

__global__ __launch_bounds__(256, 4) void gram_kernel(
    const float* __restrict__ x, float* __restrict__ partial,
    float* __restrict__ out) {
  // 39424 B -> 4 blocks/CU. Layout: raw dbuf | tileH | tileL.
  // Ebuf (64x65 f32 = 16640 B) overlays raw in the epilogue (raw is dead).
  __shared__ __align__(16) char smem[RAW_BYTES + 2 * TILE_BYTES];
  float*  raw0 = (float*)smem;
  float*  raw1 = (float*)(smem + CH_FLOATS * 4);
  __bf16* tH   = (__bf16*)(smem + RAW_BYTES);
  __bf16* tL   = (__bf16*)(smem + RAW_BYTES + TILE_BYTES);
  float*  Ebuf = (float*)smem;

  const int tid   = threadIdx.x;
  const int bidx  = blockIdx.x;       // 0..1023
  const int batch = bidx >> 2;
  const int q     = bidx & 3;
  const int w     = tid >> 6;         // wave 0..3
  const int lane  = tid & 63;
  const int ln    = lane & 31;
  const int hf    = lane >> 5;
  const int qm = w >> 1, qn = w & 1;
  const int rowA = min(qm * 32 + ln, TN - 1);  // clamped: garbage rows only
  const int rowB = min(qn * 32 + ln, TN - 1);  // feed discarded outputs
  const int nOut = qn * 32 + ln;               // true output column

  if (bidx == 0 && tid == 0) out[0] = 0.f;  // replaces memset dispatch

  const float* gbase = x + ((size_t)batch * CDIM + (size_t)q * QK) * NDIM;

  f32x16 c1, cE;
#pragma unroll
  for (int i = 0; i < 16; ++i) { c1[i] = 0.f; cE[i] = 0.f; }

  // convert-pass slice assignment (fixed per thread)
  const int s1ok = (tid < NSLICE - 256);       // 192 threads take 2nd slice
  const int n0 = tid % TN,         g0 = tid / TN;
  const int n1 = (256 + tid) % TN, g1 = (256 + tid) / TN;

  // prologue DMA: chunk 0 -> raw0
#pragma unroll
  for (int i = 0; i < 4; ++i) {
    int slot = i * 256 + tid;
    if (slot < CH_SLOTS) async_load16(gbase + slot * 4, raw0 + slot * 4);
  }

  for (int ch = 0; ch < NCHUNK; ++ch) {
    float* cur = (ch & 1) ? raw1 : raw0;
    float* nxt = (ch & 1) ? raw0 : raw1;
    __syncthreads();  // barrier A: DMA(ch) drained+visible; tiles consumed

    if (ch + 1 < NCHUNK) {  // DMA chunk ch+1; flies across convert phase
      const float* gch = gbase + (size_t)(ch + 1) * CH_FLOATS;
#pragma unroll
      for (int i = 0; i < 4; ++i) {
        int slot = i * 256 + tid;
        if (slot < CH_SLOTS) async_load16(gch + slot * 4, nxt + slot * 4);
      }
    }

    // convert-once: raw fp32 -> hi/lo bf16 fragment cells [g][n][8]
    if (n0 < NDIM) {
      const float* rp = cur + g0 * 8 * NDIM + n0;
      bf16x8 h8, l8;
#pragma unroll
      for (int j = 0; j < 8; ++j) {
        float v = rp[j * NDIM];
        __bf16 h = (__bf16)v;
        h8[j] = h;
        l8[j] = (__bf16)(v - (float)h);
      }
      *(bf16x8*)(tH + (g0 * TN + n0) * 8) = h8;
      *(bf16x8*)(tL + (g0 * TN + n0) * 8) = l8;
    }
    if (s1ok && n1 < NDIM) {
      const float* rp = cur + g1 * 8 * NDIM + n1;
      bf16x8 h8, l8;
#pragma unroll
      for (int j = 0; j < 8; ++j) {
        float v = rp[j * NDIM];
        __bf16 h = (__bf16)v;
        h8[j] = h;
        l8[j] = (__bf16)(v - (float)h);
      }
      *(bf16x8*)(tH + (g1 * TN + n1) * 8) = h8;
      *(bf16x8*)(tL + (g1 * TN + n1) * 8) = l8;
    }
    __syncthreads();  // barrier B: tiles ready

#pragma unroll
    for (int g2 = 0; g2 < 4; ++g2) {
      const int g = g2 * 2 + hf;     // k = g2*16 + hf*8 + j
      bf16x8 ah = *(const bf16x8*)(tH + (g * TN + rowA) * 8);
      bf16x8 bh;
      if (qm == qn) bh = ah;         // diagonal quadrant: A row == B row
      else          bh = *(const bf16x8*)(tH + (g * TN + rowB) * 8);
      bf16x8 bl = *(const bf16x8*)(tL + (g * TN + rowB) * 8);
      c1 = __builtin_amdgcn_mfma_f32_32x32x16_bf16(ah, bh, c1, 0, 0, 0);
      cE = __builtin_amdgcn_mfma_f32_32x32x16_bf16(ah, bl, cE, 0, 0, 0);
    }
  }

  // Epilogue: ATA = c1 + E + E^T; E^T via LDS transpose (raw is dead).
  __syncthreads();
#pragma unroll
  for (int r = 0; r < 16; ++r) {
    const int mm = qm * 32 + (r & 3) + 8 * (r >> 2) + 4 * hf;
    Ebuf[mm * ESTR + nOut] = cE[r];
  }
  __syncthreads();
  float* outp = partial + (size_t)bidx * PSIZE;
#pragma unroll
  for (int r = 0; r < 16; ++r) {
    const int mm = qm * 32 + (r & 3) + 8 * (r >> 2) + 4 * hf;
    if (mm < NDIM && nOut < NDIM)
      outp[mm * NDIM + nOut] = c1[r] + cE[r] + Ebuf[nOut * ESTR + mm];
  }
}

__global__ __launch_bounds__(64) void eigen_kernel(
    const float* __restrict__ partial, const float* __restrict__ x0,
    float* __restrict__ out) {
  __shared__ float A[NDIM * ASTR];
  __shared__ float xv[64];

  const int b = blockIdx.x;
  const int t = threadIdx.x;  // 0..63
  const float* p0 = partial + (size_t)(4 * b) * PSIZE;

  for (int idx = t; idx < NDIM * NDIM; idx += 64) {
    int r = idx / NDIM;
    int c = idx - r * NDIM;
    float v = 0.f;
#pragma unroll
    for (int qq = 0; qq < 4; ++qq) v += p0[qq * PSIZE + idx];
    A[r * ASTR + c] = v;
  }
  if (t < NDIM) xv[t] = x0[b * NDIM + t];
  __syncthreads();

  auto rayleigh_power = [&](float shift) -> float {
    for (int it = 0; it < 9; ++it) {
      float y = 0.f;
      if (t < NDIM) {
        const float* Ar = &A[t * ASTR];
#pragma unroll 7
        for (int k = 0; k < NDIM; ++k) y = fmaf(Ar[k], xv[k], y);
        y -= shift * xv[t];
      }
      float s = y * y;
#pragma unroll
      for (int o = 32; o; o >>= 1) s += __shfl_xor(s, o, 64);
      float nrm = fmaxf(sqrtf(s), 1e-12f);  // F.normalize eps
      __syncthreads();
      if (t < NDIM) xv[t] = y / nrm;
      __syncthreads();
    }
    float yy = 0.f;
    if (t < NDIM) {
      const float* Ar = &A[t * ASTR];
#pragma unroll 7
      for (int k = 0; k < NDIM; ++k) yy = fmaf(Ar[k], xv[k], yy);
      yy -= shift * xv[t];
    }
    float num = (t < NDIM) ? yy * xv[t] : 0.f;
    float den = (t < NDIM) ? xv[t] * xv[t] : 0.f;
#pragma unroll
    for (int o = 32; o; o >>= 1) {
      num += __shfl_xor(num, o, 64);
      den += __shfl_xor(den, o, 64);
    }
    return num / den;
  };

  float largest = rayleigh_power(0.f);
  float tmp = rayleigh_power(largest);  // warm start: xv == x1 already
  float smallest = tmp + largest;

  if (t == 0) {
    float r = largest / smallest - 1.f;
    atomicAdd(out, r * r * (1.0f / (float)BATCH));  // BETA = 1
  }
}

extern "C" void kernel_launch(void* const* d_in, const int* in_sizes, int n_in,
                              void* d_out, int out_size, void* d_ws,
                              size_t ws_size, hipStream_t stream) {
  const float* x  = (const float*)d_in[0];   // [256,2048,7,7] fp32
  const float* x0 = (const float*)d_in[1];   // [256,49,1] fp32 (pre-normalized)
  float* out = (float*)d_out;                // scalar fp32
  float* partial = (float*)d_ws;             // 1024 * 2401 f32 = 9.83 MB

  // PROBE: gram launched twice (idempotent). dur_us delta vs R4 (179.3)
  // measures one gram dispatch + node gap. Result stays correct: second run
  // rewrites identical partial and re-zeroes out[0] before eigen runs.
  gram_kernel<<<1024, 256, 0, stream>>>(x, partial, out);
  gram_kernel<<<1024, 256, 0, stream>>>(x, partial, out);
  eigen_kernel<<<BATCH, 64, 0, stream>>>(partial, x0, out);
}

// Round 7
// 184.874 us; speedup vs baseline: 1.8114x; 1.0717x over previous
//
#include <hip/hip_runtime.h>
#include <hip/hip_bf16.h>
#include <stdint.h>

// OFPenalty: per-batch Gram (49x49 from 2048x49) -> two 9-step power
// iterations -> penalty scalar.
//
// R7 = R4 gram verbatim + restructured eigen:
//  - eigen is now idempotent (writes pen[b]; final 1-block reduce kernel
//    sums) and is launched TWICE as a timing probe (delta = eigen cost).
//  - eigen latency fixes: A-row hoisted to 49 VGPRs (once), 4-way ILP dot
//    product, float4 broadcast xv reads.
// Known from probes: harness fixed ~95 us; gram(+gap) ~19 us warm; the
// unexplained ~60 us of R4 is eigen and/or cold-gram latency — this round
// splits them.

#define BATCH 256
#define CDIM  2048
#define NDIM  49
#define QK    512                    // C rows per block (2048/4)
#define CHUNK 64                     // k rows per LDS stage
#define NCHUNK (QK / CHUNK)          // 8
#define CH_FLOATS (CHUNK * NDIM)     // 3136
#define CH_SLOTS  (CH_FLOATS / 4)    // 784 16B DMA slots
#define TN    56                     // tile n capacity (>=49; rows clamp)
#define NSLICE (8 * TN)              // 448 (g,n) cells per chunk
#define TILE_BYTES (8 * TN * 8 * 2)  // 7168 per hi/lo tile
#define RAW_BYTES (2 * CH_FLOATS * 4)// 25088 (dbuf)
#define PSIZE (NDIM * NDIM)          // 2401
#define ESTR  65                     // Ebuf row stride (f32)
#define ASTR  53                     // eigen A row stride (f32)

typedef __bf16 bf16x8 __attribute__((ext_vector_type(8)));
typedef float  f32x16 __attribute__((ext_vector_type(16)));

__device__ inline void async_load16(const float* g, float* l) {
  __builtin_amdgcn_global_load_lds(
      (const __attribute__((address_space(1))) void*)g,
      (__attribute__((address_space(3))) void*)l,
      16 /*bytes*/, 0 /*offset*/, 0 /*aux*/);
}

__global__ __launch_bounds__(256, 4) void gram_kernel(
    const float* __restrict__ x, float* __restrict__ partial) {
  // 39424 B -> 4 blocks/CU. Layout: raw dbuf | tileH | tileL.
  // Ebuf (64x65 f32 = 16640 B) overlays raw in the epilogue (raw is dead).
  __shared__ __align__(16) char smem[RAW_BYTES + 2 * TILE_BYTES];
  float*  raw0 = (float*)smem;
  float*  raw1 = (float*)(smem + CH_FLOATS * 4);
  __bf16* tH   = (__bf16*)(smem + RAW_BYTES);
  __bf16* tL   = (__bf16*)(smem + RAW_BYTES + TILE_BYTES);
  float*  Ebuf = (float*)smem;

  const int tid   = threadIdx.x;
  const int bidx  = blockIdx.x;       // 0..1023
  const int batch = bidx >> 2;
  const int q     = bidx & 3;
  const int w     = tid >> 6;         // wave 0..3
  const int lane  = tid & 63;
  const int ln    = lane & 31;
  const int hf    = lane >> 5;
  const int qm = w >> 1, qn = w & 1;
  const int rowA = min(qm * 32 + ln, TN - 1);  // clamped: garbage rows only
  const int rowB = min(qn * 32 + ln, TN - 1);  // feed discarded outputs
  const int nOut = qn * 32 + ln;               // true output column

  const float* gbase = x + ((size_t)batch * CDIM + (size_t)q * QK) * NDIM;

  f32x16 c1, cE;
#pragma unroll
  for (int i = 0; i < 16; ++i) { c1[i] = 0.f; cE[i] = 0.f; }

  // convert-pass slice assignment (fixed per thread)
  const int s1ok = (tid < NSLICE - 256);       // 192 threads take 2nd slice
  const int n0 = tid % TN,         g0 = tid / TN;
  const int n1 = (256 + tid) % TN, g1 = (256 + tid) / TN;

  // prologue DMA: chunk 0 -> raw0
#pragma unroll
  for (int i = 0; i < 4; ++i) {
    int slot = i * 256 + tid;
    if (slot < CH_SLOTS) async_load16(gbase + slot * 4, raw0 + slot * 4);
  }

  for (int ch = 0; ch < NCHUNK; ++ch) {
    float* cur = (ch & 1) ? raw1 : raw0;
    float* nxt = (ch & 1) ? raw0 : raw1;
    __syncthreads();  // barrier A: DMA(ch) drained+visible; tiles consumed

    if (ch + 1 < NCHUNK) {  // DMA chunk ch+1; flies across convert phase
      const float* gch = gbase + (size_t)(ch + 1) * CH_FLOATS;
#pragma unroll
      for (int i = 0; i < 4; ++i) {
        int slot = i * 256 + tid;
        if (slot < CH_SLOTS) async_load16(gch + slot * 4, nxt + slot * 4);
      }
    }

    // convert-once: raw fp32 -> hi/lo bf16 fragment cells [g][n][8]
    if (n0 < NDIM) {
      const float* rp = cur + g0 * 8 * NDIM + n0;
      bf16x8 h8, l8;
#pragma unroll
      for (int j = 0; j < 8; ++j) {
        float v = rp[j * NDIM];
        __bf16 h = (__bf16)v;
        h8[j] = h;
        l8[j] = (__bf16)(v - (float)h);
      }
      *(bf16x8*)(tH + (g0 * TN + n0) * 8) = h8;
      *(bf16x8*)(tL + (g0 * TN + n0) * 8) = l8;
    }
    if (s1ok && n1 < NDIM) {
      const float* rp = cur + g1 * 8 * NDIM + n1;
      bf16x8 h8, l8;
#pragma unroll
      for (int j = 0; j < 8; ++j) {
        float v = rp[j * NDIM];
        __bf16 h = (__bf16)v;
        h8[j] = h;
        l8[j] = (__bf16)(v - (float)h);
      }
      *(bf16x8*)(tH + (g1 * TN + n1) * 8) = h8;
      *(bf16x8*)(tL + (g1 * TN + n1) * 8) = l8;
    }
    __syncthreads();  // barrier B: tiles ready

#pragma unroll
    for (int g2 = 0; g2 < 4; ++g2) {
      const int g = g2 * 2 + hf;     // k = g2*16 + hf*8 + j
      bf16x8 ah = *(const bf16x8*)(tH + (g * TN + rowA) * 8);
      bf16x8 bh;
      if (qm == qn) bh = ah;         // diagonal quadrant: A row == B row
      else          bh = *(const bf16x8*)(tH + (g * TN + rowB) * 8);
      bf16x8 bl = *(const bf16x8*)(tL + (g * TN + rowB) * 8);
      c1 = __builtin_amdgcn_mfma_f32_32x32x16_bf16(ah, bh, c1, 0, 0, 0);
      cE = __builtin_amdgcn_mfma_f32_32x32x16_bf16(ah, bl, cE, 0, 0, 0);
    }
  }

  // Epilogue: ATA = c1 + E + E^T; E^T via LDS transpose (raw is dead).
  __syncthreads();
#pragma unroll
  for (int r = 0; r < 16; ++r) {
    const int mm = qm * 32 + (r & 3) + 8 * (r >> 2) + 4 * hf;
    Ebuf[mm * ESTR + nOut] = cE[r];
  }
  __syncthreads();
  float* outp = partial + (size_t)bidx * PSIZE;
#pragma unroll
  for (int r = 0; r < 16; ++r) {
    const int mm = qm * 32 + (r & 3) + 8 * (r >> 2) + 4 * hf;
    if (mm < NDIM && nOut < NDIM)
      outp[mm * NDIM + nOut] = c1[r] + cE[r] + Ebuf[nOut * ESTR + mm];
  }
}

// Idempotent eigen: writes pen[b] (no atomic), so it can be launched twice
// as a probe. Latency fixes: A-row in 49 VGPRs, 4-way ILP dot, float4 xv.
__global__ __launch_bounds__(64) void eigen_kernel(
    const float* __restrict__ partial, const float* __restrict__ x0,
    float* __restrict__ pen) {
  __shared__ float A[NDIM * ASTR];
  __shared__ __align__(16) float xv[64];

  const int b = blockIdx.x;
  const int t = threadIdx.x;  // 0..63
  const float* p0 = partial + (size_t)(4 * b) * PSIZE;

  for (int idx = t; idx < PSIZE; idx += 64) {
    int r = idx / NDIM;
    int c = idx - r * NDIM;
    float v = 0.f;
#pragma unroll
    for (int qq = 0; qq < 4; ++qq) v += p0[qq * PSIZE + idx];
    A[r * ASTR + c] = v;
  }
  if (t < NDIM) xv[t] = x0[b * NDIM + t];
  else          xv[t] = 0.f;           // keep lanes 49..63 finite
  __syncthreads();

  // Hoist this lane's A row into registers (A is constant from here on).
  const int rowbase = min(t, NDIM - 1) * ASTR;
  float Ar[NDIM];
#pragma unroll
  for (int k = 0; k < NDIM; ++k) Ar[k] = A[rowbase + k];
  const bool act = (t < NDIM);

  auto matvec = [&](float shift) -> float {
    const float4* xv4 = (const float4*)xv;
    float a0 = 0.f, a1 = 0.f, a2 = 0.f, a3 = 0.f;
#pragma unroll
    for (int j = 0; j < 12; ++j) {     // broadcast float4 reads of xv
      float4 xq = xv4[j];
      a0 = fmaf(Ar[4 * j + 0], xq.x, a0);
      a1 = fmaf(Ar[4 * j + 1], xq.y, a1);
      a2 = fmaf(Ar[4 * j + 2], xq.z, a2);
      a3 = fmaf(Ar[4 * j + 3], xq.w, a3);
    }
    float y = fmaf(Ar[48], xv[48], (a0 + a1) + (a2 + a3));
    return y - shift * xv[t];
  };

  auto rayleigh_power = [&](float shift) -> float {
    for (int it = 0; it < 9; ++it) {
      float y = matvec(shift);
      float s = act ? y * y : 0.f;
#pragma unroll
      for (int o = 32; o; o >>= 1) s += __shfl_xor(s, o, 64);
      float nrm = fmaxf(sqrtf(s), 1e-12f);  // F.normalize eps
      __syncthreads();
      if (act) xv[t] = y / nrm;
      __syncthreads();
    }
    float yy = matvec(shift);
    float num = act ? yy * xv[t] : 0.f;
    float den = act ? xv[t] * xv[t] : 0.f;
#pragma unroll
    for (int o = 32; o; o >>= 1) {
      num += __shfl_xor(num, o, 64);
      den += __shfl_xor(den, o, 64);
    }
    return num / den;
  };

  float largest = rayleigh_power(0.f);
  float tmp = rayleigh_power(largest);  // warm start: xv == x1 already
  float smallest = tmp + largest;

  if (t == 0) {
    float r = largest / smallest - 1.f;
    pen[b] = r * r;                     // BETA = 1; /BATCH in reduce
  }
}

__global__ __launch_bounds__(64) void reduce_kernel(
    const float* __restrict__ pen, float* __restrict__ out) {
  const int t = threadIdx.x;
  float s = pen[t] + pen[t + 64] + pen[t + 128] + pen[t + 192];
#pragma unroll
  for (int o = 32; o; o >>= 1) s += __shfl_xor(s, o, 64);
  if (t == 0) out[0] = s * (1.0f / (float)BATCH);
}

extern "C" void kernel_launch(void* const* d_in, const int* in_sizes, int n_in,
                              void* d_out, int out_size, void* d_ws,
                              size_t ws_size, hipStream_t stream) {
  const float* x  = (const float*)d_in[0];   // [256,2048,7,7] fp32
  const float* x0 = (const float*)d_in[1];   // [256,49,1] fp32 (pre-normalized)
  float* out = (float*)d_out;                // scalar fp32
  float* partial = (float*)d_ws;             // 1024 * 2401 f32 = 9.83 MB
  float* pen = partial + 1024 * PSIZE;       // 256 f32

  gram_kernel<<<1024, 256, 0, stream>>>(x, partial);
  // PROBE: eigen launched twice (idempotent: writes pen[b] only).
  // Delta vs single launch = true eigen cost.
  eigen_kernel<<<BATCH, 64, 0, stream>>>(partial, x0, pen);
  eigen_kernel<<<BATCH, 64, 0, stream>>>(partial, x0, pen);
  reduce_kernel<<<1, 64, 0, stream>>>(pen, out);
}